// Round 5
// baseline (8227.942 us; speedup 1.0000x reference)
//
#include <hip/hip_runtime.h>

// ---------- types ----------
typedef __attribute__((ext_vector_type(8))) short short8;
typedef __attribute__((ext_vector_type(4))) float f32x4;
typedef __attribute__((ext_vector_type(8))) unsigned short ushort8;

__device__ inline float bf2f(unsigned short u) {
    unsigned int x = ((unsigned int)u) << 16;
    float f; __builtin_memcpy(&f, &x, 4); return f;
}
__device__ inline unsigned short f2bf(float f) {
    unsigned int x; __builtin_memcpy(&x, &f, 4);
    x += 0x7fffu + ((x >> 16) & 1u);
    return (unsigned short)(x >> 16);
}
// flag: 0 = fp32, 1 = bf16, 2 = fp16
__device__ inline float readf(const void* p, size_t i, int flag) {
    if (flag == 1) return bf2f(((const unsigned short*)p)[i]);
    if (flag == 2) return (float)(((const _Float16*)p)[i]);
    return ((const float*)p)[i];
}
__device__ inline float h2f(unsigned short u) {
    _Float16 h; __builtin_memcpy(&h, &u, 2); return (float)h;
}

// async global->LDS, 16B per lane. LDS dest must be wave-uniform base + lane*16.
__device__ __forceinline__ void gld_lds16(const unsigned short* g, unsigned short* l) {
    __builtin_amdgcn_global_load_lds(
        (const __attribute__((address_space(1))) unsigned int*)g,
        (__attribute__((address_space(3))) unsigned int*)l, 16, 0, 0);
}

// ---------- dtype detect from g1[0] == 1.0 ----------
__global__ void detect_dtype(const unsigned int* g1, int* flag) {
    unsigned int w = g1[0];
    int f = 0;
    if ((w & 0xFFFFu) == 0x3F80u) f = 1;       // bf16 1.0 pair
    else if ((w & 0xFFFFu) == 0x3C00u) f = 2;  // fp16 1.0 pair
    *flag = f;                                  // fp32 1.0 low16 = 0x0000 -> 0
}

// ---------- per-layer transpose -> bf16; out[z*outLS + c*R + r] = in[layer0+z][r][c] ----------
__global__ void transpose_in(const void* __restrict__ in, unsigned short* __restrict__ out,
                             int R, int Cc, size_t inBS, int layer0, size_t outLS,
                             const int* flagp) {
    int flag = *flagp;
    int layer = layer0 + blockIdx.z;
    unsigned short* op = out + (size_t)blockIdx.z * outLS;
    __shared__ unsigned short tile[32][33];
    int c0 = blockIdx.x * 32, r0 = blockIdx.y * 32;
#pragma unroll
    for (int j = 0; j < 4; j++) {
        int r = r0 + threadIdx.y + j * 8;
        size_t src = (size_t)layer * inBS + (size_t)r * Cc + c0 + threadIdx.x;
        tile[threadIdx.y + j * 8][threadIdx.x] = f2bf(readf(in, src, flag));
    }
    __syncthreads();
#pragma unroll
    for (int j = 0; j < 4; j++) {
        int c = c0 + threadIdx.y + j * 8;
        op[(size_t)c * R + r0 + threadIdx.x] = tile[threadIdx.x][threadIdx.y + j * 8];
    }
}

// ---------- feat convert (x8 vectorized): in -> fp32 master + bf16 shadow ----------
__global__ void cvt_feat(const void* __restrict__ in, float* __restrict__ f32,
                         unsigned short* __restrict__ fbf, int n, const int* flagp) {
    int flag = *flagp;
    int i = (blockIdx.x * 256 + threadIdx.x) * 8;
    if (i >= n) return;
    float v[8];
    if (flag == 1) {
        ushort8 r = *reinterpret_cast<const ushort8*>((const unsigned short*)in + i);
#pragma unroll
        for (int j = 0; j < 8; j++) { unsigned short us = r[j]; v[j] = bf2f(us); }
    } else if (flag == 2) {
        ushort8 r = *reinterpret_cast<const ushort8*>((const unsigned short*)in + i);
#pragma unroll
        for (int j = 0; j < 8; j++) { unsigned short us = r[j]; v[j] = h2f(us); }
    } else {
        float4 a = *reinterpret_cast<const float4*>((const float*)in + i);
        float4 b = *reinterpret_cast<const float4*>((const float*)in + i + 4);
        v[0] = a.x; v[1] = a.y; v[2] = a.z; v[3] = a.w;
        v[4] = b.x; v[5] = b.y; v[6] = b.z; v[7] = b.w;
    }
    *reinterpret_cast<float4*>(f32 + i) = make_float4(v[0], v[1], v[2], v[3]);
    *reinterpret_cast<float4*>(f32 + i + 4) = make_float4(v[4], v[5], v[6], v[7]);
    ushort8 o;
#pragma unroll
    for (int j = 0; j < 8; j++) o[j] = f2bf(v[j]);
    *reinterpret_cast<ushort8*>(fbf + i) = o;
}

// ---------- MFMA GEMM (round-1/3 proven m97 structure): C = A[.,K] @ BT[.,K]^T ----------
// global_load_lds width=16 staging into linear 128x32 LDS tiles.
// A split: k0 < splitK -> A, else A2 at k0-splitK (both lda).
// Block-uniform column split: colBase < colSplit -> C (ldc) else C2 (ldc2, col-colSplit).
__global__ __launch_bounds__(256) void gemm_bf16(
    const unsigned short* __restrict__ A, const unsigned short* __restrict__ A2,
    const unsigned short* __restrict__ BT, unsigned short* __restrict__ C,
    unsigned short* __restrict__ C2,
    int K, int lda, int splitK, int ldb, int ldc, int colSplit, int ldc2, int relu) {
    __shared__ __align__(16) unsigned short As[128 * 32];
    __shared__ __align__(16) unsigned short Bs[128 * 32];
    int t = threadIdx.x;
    int rowBase = blockIdx.y * 128, colBase = blockIdx.x * 128;
    int lane = t & 63, wave = t >> 6;
    int wm = (wave & 1) * 64, wn = (wave >> 1) * 64;
    int mrow = lane & 15, quad = lane >> 4;
    f32x4 acc[4][4];
#pragma unroll
    for (int i = 0; i < 4; i++)
#pragma unroll
        for (int j = 0; j < 4; j++) acc[i][j] = (f32x4){0.f, 0.f, 0.f, 0.f};

    // staging geometry: thread t covers 16B chunk at (row = t>>2, col8 = (t&3)*8)
    // and a second chunk 64 rows down. LDS elem offset = t*8 (and 2048 + t*8).
    int r0 = t >> 2, c0 = (t & 3) * 8;
    int r1 = r0 + 64;

    for (int k0 = 0; k0 < K; k0 += 32) {
        const unsigned short* Ab; int kk;
        if (k0 < splitK) { Ab = A; kk = k0; } else { Ab = A2; kk = k0 - splitK; }
        __syncthreads();  // previous iteration's LDS reads complete
        gld_lds16(Ab + (size_t)(rowBase + r0) * lda + kk + c0, &As[t * 8]);
        gld_lds16(Ab + (size_t)(rowBase + r1) * lda + kk + c0, &As[2048 + t * 8]);
        gld_lds16(BT + (size_t)(colBase + r0) * ldb + k0 + c0, &Bs[t * 8]);
        gld_lds16(BT + (size_t)(colBase + r1) * ldb + k0 + c0, &Bs[2048 + t * 8]);
        __syncthreads();  // compiler drains vmcnt(0) before barrier -> data in LDS
        short8 af[4], bfr[4];
#pragma unroll
        for (int mt = 0; mt < 4; mt++)
            af[mt] = *reinterpret_cast<const short8*>(&As[(wm + mt * 16 + mrow) * 32 + quad * 8]);
#pragma unroll
        for (int nt = 0; nt < 4; nt++)
            bfr[nt] = *reinterpret_cast<const short8*>(&Bs[(wn + nt * 16 + mrow) * 32 + quad * 8]);
#pragma unroll
        for (int mt = 0; mt < 4; mt++)
#pragma unroll
            for (int nt = 0; nt < 4; nt++)
                acc[mt][nt] = __builtin_amdgcn_mfma_f32_16x16x32_bf16(af[mt], bfr[nt], acc[mt][nt], 0, 0, 0);
    }
    // block-uniform output region select (no per-element divergence)
    unsigned short* Cout; int cb, ldco;
    if (colBase < colSplit) { Cout = C; cb = colBase; ldco = ldc; }
    else { Cout = C2; cb = colBase - colSplit; ldco = ldc2; }
#pragma unroll
    for (int mt = 0; mt < 4; mt++)
#pragma unroll
        for (int nt = 0; nt < 4; nt++)
#pragma unroll
            for (int r = 0; r < 4; r++) {
                int row = rowBase + wm + mt * 16 + quad * 4 + r;
                int col = cb + wn + nt * 16 + mrow;
                float v = acc[mt][nt][r];
                if (relu) v = fmaxf(v, 0.f);
                Cout[(size_t)row * ldco + col] = f2bf(v);
            }
}

// ---------- KV reduce (register-tiled 8x8, round-3 proven) ----------
// KV[n,h,d,e] += sum_s elu1(k[s,d]) * v[s,e]; Ksum[n,h,d] += sum elu1(k).
// kv buffer: [rows,1024] cols 0..511 = k, 512..1023 = v. grid (16 schunk, 8 h, nBatch)
__global__ __launch_bounds__(256) void kv_reduce(
    const unsigned short* __restrict__ kv, float* __restrict__ KV, float* __restrict__ Ksum) {
    __shared__ float smem[4096];          // kf = smem[0..2047], vf = smem[2048..4095]
    float* kf = smem;
    float* vf = smem + 2048;
    int t = threadIdx.x;
    int sc = blockIdx.x, h = blockIdx.y, n = blockIdx.z;
    int w = t >> 6, u = t & 63;
    int d0 = (u >> 3) * 8, e0 = (u & 7) * 8;
    float acc[8][8];
#pragma unroll
    for (int i = 0; i < 8; i++)
#pragma unroll
        for (int j = 0; j < 8; j++) acc[i][j] = 0.f;
    float ks[8];
#pragma unroll
    for (int i = 0; i < 8; i++) ks[i] = 0.f;

    int rl = t >> 3, dg = (t & 7) << 3;   // staging: 32 rows x 64 cols
    for (int sb = 0; sb < 8; sb++) {
        int srow = n * 4096 + sc * 256 + sb * 32 + rl;
        const unsigned short* kp = kv + (size_t)srow * 1024 + h * 64 + dg;
        ushort8 kr = *reinterpret_cast<const ushort8*>(kp);
        ushort8 vr = *reinterpret_cast<const ushort8*>(kp + 512);
        __syncthreads();
#pragma unroll
        for (int j = 0; j < 8; j++) {
            unsigned short ku = kr[j], vu = vr[j];
            float x = bf2f(ku);
            kf[rl * 64 + dg + j] = x > 0.f ? x + 1.f : __expf(x);
            vf[rl * 64 + dg + j] = bf2f(vu);
        }
        __syncthreads();
        // this wave's 8 s-rows of the 32-row tile
#pragma unroll
        for (int r = 0; r < 8; r++) {
            int s = w * 8 + r;
            float4 ka = *reinterpret_cast<const float4*>(&kf[s * 64 + d0]);
            float4 kb = *reinterpret_cast<const float4*>(&kf[s * 64 + d0 + 4]);
            float4 va = *reinterpret_cast<const float4*>(&vf[s * 64 + e0]);
            float4 vb = *reinterpret_cast<const float4*>(&vf[s * 64 + e0 + 4]);
            float kreg[8] = {ka.x, ka.y, ka.z, ka.w, kb.x, kb.y, kb.z, kb.w};
            float vreg[8] = {va.x, va.y, va.z, va.w, vb.x, vb.y, vb.z, vb.w};
#pragma unroll
            for (int i = 0; i < 8; i++) ks[i] += kreg[i];
#pragma unroll
            for (int i = 0; i < 8; i++)
#pragma unroll
                for (int j = 0; j < 8; j++) acc[i][j] += kreg[i] * vreg[j];
        }
    }
    // merge the 4 waves' duplicated 64x64 tiles in LDS
    __syncthreads();
    if (w == 0) {
#pragma unroll
        for (int i = 0; i < 8; i++)
#pragma unroll
            for (int j = 0; j < 8; j++) smem[(d0 + i) * 64 + e0 + j] = acc[i][j];
    }
    __syncthreads();
#pragma unroll
    for (int ww = 1; ww < 4; ww++) {
        if (w == ww) {
#pragma unroll
            for (int i = 0; i < 8; i++)
#pragma unroll
                for (int j = 0; j < 8; j++) smem[(d0 + i) * 64 + e0 + j] += acc[i][j];
        }
        __syncthreads();
    }
    float* dst = KV + ((size_t)(n * 8 + h) << 12);
#pragma unroll
    for (int i = 0; i < 16; i++) {
        int idx = t + i * 256;
        atomicAdd(dst + idx, smem[idx]);
    }
    if ((u & 7) == 0) {
#pragma unroll
        for (int i = 0; i < 8; i++)
            atomicAdd(Ksum + (n * 8 + h) * 64 + d0 + i, ks[i]);
    }
}

// ---------- attention message (wave-local, zero barriers, round-1 proven) ----------
// msg[l, h*64+e] = elu1(Q).KV / (elu1(Q).Ksum + eps). grid (32 rowchunk, 4 headpair, nBatch)
__global__ __launch_bounds__(256) void attn_msg(
    const unsigned short* __restrict__ q, const float* __restrict__ KV,
    const float* __restrict__ Ksum, unsigned short* __restrict__ msg) {
    __shared__ __align__(16) float qsh[4][128];
    int t = threadIdx.x;
    int rcb = blockIdx.x, hp = blockIdx.y, n = blockIdx.z;
    int h0 = hp * 2;
    int w = t >> 6, lane = t & 63;

    // hoist this thread's two KV columns (e = lane) into registers
    const float* kvp = KV + (size_t)(n * 8 + h0) * 4096 + lane;
    float kv0[64], kv1[64];
#pragma unroll
    for (int d = 0; d < 64; d++) kv0[d] = kvp[d * 64];
#pragma unroll
    for (int d = 0; d < 64; d++) kv1[d] = kvp[4096 + d * 64];
    const float* ksp = Ksum + (size_t)(n * 8 + h0) * 64;
    float ks0 = ksp[lane * 2], ks1 = ksp[lane * 2 + 1];  // spans [head0 | head1]

    for (int it = 0; it < 32; it++) {
        int row = rcb * 128 + it * 4 + w;
        unsigned int raw = *reinterpret_cast<const unsigned int*>(
            q + (size_t)(n * 4096 + row) * 512 + h0 * 64 + lane * 2);
        float x0 = bf2f((unsigned short)(raw & 0xFFFFu));
        float x1 = bf2f((unsigned short)(raw >> 16));
        x0 = x0 > 0.f ? x0 + 1.f : __expf(x0);
        x1 = x1 > 0.f ? x1 + 1.f : __expf(x1);
        // z: halves-reduction (xor offsets 1..16 stay within 32-lane halves)
        float part = x0 * ks0 + x1 * ks1;
#pragma unroll
        for (int off = 1; off < 32; off <<= 1) part += __shfl_xor(part, off, 64);
        float z0 = 1.f / (__shfl(part, 0, 64) + 1e-6f);
        float z1 = 1.f / (__shfl(part, 32, 64) + 1e-6f);
        // wave-local broadcast of the q row (in-wave DS ordering, no barrier)
        qsh[w][lane * 2] = x0;
        qsh[w][lane * 2 + 1] = x1;
        float a0 = 0.f, a1 = 0.f;
#pragma unroll
        for (int d4 = 0; d4 < 16; d4++) {
            float4 qa = *reinterpret_cast<const float4*>(&qsh[w][d4 * 4]);
            float4 qb = *reinterpret_cast<const float4*>(&qsh[w][64 + d4 * 4]);
            a0 += qa.x * kv0[d4 * 4] + qa.y * kv0[d4 * 4 + 1] +
                  qa.z * kv0[d4 * 4 + 2] + qa.w * kv0[d4 * 4 + 3];
            a1 += qb.x * kv1[d4 * 4] + qb.y * kv1[d4 * 4 + 1] +
                  qb.z * kv1[d4 * 4 + 2] + qb.w * kv1[d4 * 4 + 3];
        }
        unsigned short* mp = msg + (size_t)(n * 4096 + row) * 512 + h0 * 64;
        mp[lane] = f2bf(a0 * z0);
        mp[64 + lane] = f2bf(a1 * z1);
    }
}

// ---------- LayerNorm (C=512), wave per row ----------
__global__ __launch_bounds__(256) void ln_fwd(
    const unsigned short* __restrict__ in, unsigned short* __restrict__ out,
    const void* __restrict__ g, const void* __restrict__ b, int layer, const int* flagp) {
    int flag = *flagp;
    int wave = threadIdx.x >> 6, lane = threadIdx.x & 63;
    size_t row = (size_t)blockIdx.x * 4 + wave;
    ushort8 raw = *reinterpret_cast<const ushort8*>(in + row * 512 + lane * 8);
    float x[8], s = 0.f, sq = 0.f;
#pragma unroll
    for (int j = 0; j < 8; j++) { unsigned short us = raw[j]; x[j] = bf2f(us); s += x[j]; sq += x[j] * x[j]; }
#pragma unroll
    for (int off = 1; off < 64; off <<= 1) { s += __shfl_xor(s, off, 64); sq += __shfl_xor(sq, off, 64); }
    float mu = s * (1.f / 512.f);
    float var = fmaxf(sq * (1.f / 512.f) - mu * mu, 0.f);
    float rs = rsqrtf(var + 1e-5f);
    int c = layer * 512 + lane * 8;
    ushort8 o;
#pragma unroll
    for (int j = 0; j < 8; j++) {
        float gv = readf(g, c + j, flag);
        float bv = readf(b, c + j, flag);
        o[j] = f2bf((x[j] - mu) * rs * gv + bv);
    }
    *reinterpret_cast<ushort8*>(out + row * 512 + lane * 8) = o;
}

// ---------- LayerNorm + residual: f32 += LN(u); refresh bf16 shadow ----------
__global__ __launch_bounds__(256) void ln_res(
    const unsigned short* __restrict__ u, float* __restrict__ f32,
    unsigned short* __restrict__ fbf, const void* __restrict__ g,
    const void* __restrict__ b, int layer, const int* flagp) {
    int flag = *flagp;
    int wave = threadIdx.x >> 6, lane = threadIdx.x & 63;
    size_t row = (size_t)blockIdx.x * 4 + wave;
    ushort8 raw = *reinterpret_cast<const ushort8*>(u + row * 512 + lane * 8);
    float x[8], s = 0.f, sq = 0.f;
#pragma unroll
    for (int j = 0; j < 8; j++) { unsigned short us = raw[j]; x[j] = bf2f(us); s += x[j]; sq += x[j] * x[j]; }
#pragma unroll
    for (int off = 1; off < 64; off <<= 1) { s += __shfl_xor(s, off, 64); sq += __shfl_xor(sq, off, 64); }
    float mu = s * (1.f / 512.f);
    float var = fmaxf(sq * (1.f / 512.f) - mu * mu, 0.f);
    float rs = rsqrtf(var + 1e-5f);
    int c = layer * 512 + lane * 8;
    float* fp = f32 + row * 512 + lane * 8;
    float4 f0 = *reinterpret_cast<float4*>(fp);
    float4 f1 = *reinterpret_cast<float4*>(fp + 4);
    float fv[8] = {f0.x, f0.y, f0.z, f0.w, f1.x, f1.y, f1.z, f1.w};
    ushort8 o;
#pragma unroll
    for (int j = 0; j < 8; j++) {
        float gv = readf(g, c + j, flag);
        float bv = readf(b, c + j, flag);
        float y = (x[j] - mu) * rs * gv + bv;
        fv[j] += y;
        o[j] = f2bf(fv[j]);
    }
    f0 = make_float4(fv[0], fv[1], fv[2], fv[3]);
    f1 = make_float4(fv[4], fv[5], fv[6], fv[7]);
    *reinterpret_cast<float4*>(fp) = f0;
    *reinterpret_cast<float4*>(fp + 4) = f1;
    *reinterpret_cast<ushort8*>(fbf + row * 512 + lane * 8) = o;
}

// ---------- host ----------
// Output d_out is FLOAT32 (reference output dtype), (feat0, feat1) concat flat.
// ROUND 10 (= round-9 design, compile-fixed: no address-of-vector-element):
// self layers batched at M=32768 with fused QKV GEMM (block-uniform col-split
// epilogue); cross layers keep round-3-proven path; cvt_feat vectorized x8.
extern "C" void kernel_launch(void* const* d_in, const int* in_sizes, int n_in,
                              void* d_out, int out_size, void* d_ws, size_t ws_size,
                              hipStream_t stream) {
    char* ws = (char*)d_ws;
    size_t o = 0;
    auto take = [&](size_t bytes) { char* p = ws + o; o += (bytes + 1023) & ~(size_t)1023; return p; };
    // per-layer fallback weight buffers (always reserved; 5 MB)
    unsigned short* wqTl  = (unsigned short*)take(262144ull * 2);
    unsigned short* wkvTl = (unsigned short*)take(524288ull * 2);
    unsigned short* wmTl  = (unsigned short*)take(262144ull * 2);
    unsigned short* w1Tl  = (unsigned short*)take(1048576ull * 2);
    unsigned short* w2Tl  = (unsigned short*)take(524288ull * 2);
    float* f32_0 = (float*)take(8388608ull * 4);
    float* f32_1 = (float*)take(8388608ull * 4);   // contiguous after f32_0
    unsigned short* fbf0  = (unsigned short*)take(8388608ull * 2);
    unsigned short* fbf1  = (unsigned short*)take(8388608ull * 2);  // contiguous after fbf0
    // pools sized for batched M=32768
    unsigned short* poolA = (unsigned short*)take(16777216ull * 2);
    unsigned short* poolB = (unsigned short*)take(33554432ull * 2);
    unsigned short* poolC = (unsigned short*)take(16777216ull * 2);
    float* kvws = (float*)take(266240ull * 4);  // KV[8*8*64*64] then Ksum[8*8*64]
    int* flagp = (int*)take(64);
    float* ksumws = kvws + 262144;

    // batched all-layer weight area (60 MB), used only if workspace allows
    const size_t WPER = 2621440ull;  // shorts per layer: wq|wk|wv|wm|w1|w2
    bool preT = ws_size >= o + WPER * 12ull * 2ull + 65536ull;
    unsigned short* wAll = preT ? (unsigned short*)take(WPER * 12ull * 2ull) : nullptr;

    detect_dtype<<<1, 1, 0, stream>>>((const unsigned int*)d_in[8], flagp);
    cvt_feat<<<4096, 256, 0, stream>>>(d_in[0], f32_0, fbf0, 8388608, flagp);
    cvt_feat<<<4096, 256, 0, stream>>>(d_in[1], f32_1, fbf1, 8388608, flagp);

    if (preT) {  // all 12 layers transposed in 6 dispatches
        transpose_in<<<dim3(16, 16, 12), dim3(32, 8), 0, stream>>>(d_in[2], wAll,           512, 512,  262144, 0, WPER, flagp);
        transpose_in<<<dim3(16, 16, 12), dim3(32, 8), 0, stream>>>(d_in[3], wAll + 262144,  512, 512,  262144, 0, WPER, flagp);
        transpose_in<<<dim3(16, 16, 12), dim3(32, 8), 0, stream>>>(d_in[4], wAll + 524288,  512, 512,  262144, 0, WPER, flagp);
        transpose_in<<<dim3(16, 16, 12), dim3(32, 8), 0, stream>>>(d_in[5], wAll + 786432,  512, 512,  262144, 0, WPER, flagp);
        transpose_in<<<dim3(32, 32, 12), dim3(32, 8), 0, stream>>>(d_in[6], wAll + 1048576, 1024, 1024, 1048576, 0, WPER, flagp);
        transpose_in<<<dim3(16, 32, 12), dim3(32, 8), 0, stream>>>(d_in[7], wAll + 2097152, 1024, 512,  524288, 0, WPER, flagp);
    }

    // unbatched encoder (M=16384), used for cross layers and fallback
    auto enc1 = [&](float* xf32, unsigned short* xbf, const unsigned short* srcbf, int l,
                    const unsigned short* wq_p, const unsigned short* wkv_p, const unsigned short* wm_p,
                    const unsigned short* w1_p, const unsigned short* w2_p) {
        gemm_bf16<<<dim3(4, 128), 256, 0, stream>>>(xbf, xbf, wq_p, poolA, poolA,
            512, 512, 512, 512, 512, 512, 512, 0);
        gemm_bf16<<<dim3(8, 128), 256, 0, stream>>>(srcbf, srcbf, wkv_p, poolB, poolB,
            512, 512, 512, 512, 1024, 1024, 1024, 0);
        (void)hipMemsetAsync(kvws, 0, 266240ull * 4, stream);
        kv_reduce<<<dim3(16, 8, 4), 256, 0, stream>>>(poolB, kvws, ksumws);
        attn_msg<<<dim3(32, 4, 4), 256, 0, stream>>>(poolA, kvws, ksumws, poolC);
        gemm_bf16<<<dim3(4, 128), 256, 0, stream>>>(poolC, poolC, wm_p, poolA, poolA,
            512, 512, 512, 512, 512, 512, 512, 0);
        ln_fwd<<<4096, 256, 0, stream>>>(poolA, poolC, d_in[8], d_in[9], l, flagp);
        gemm_bf16<<<dim3(8, 128), 256, 0, stream>>>(xbf, poolC, w1_p, poolB, poolB,
            1024, 512, 512, 1024, 1024, 1024, 1024, 1);
        gemm_bf16<<<dim3(4, 128), 256, 0, stream>>>(poolB, poolB, w2_p, poolA, poolA,
            1024, 1024, 1024, 1024, 512, 512, 512, 0);
        ln_res<<<4096, 256, 0, stream>>>(poolA, xf32, xbf, d_in[10], d_in[11], l, flagp);
    };

    // batched self-layer encoder (M=32768 over contiguous fbf0|fbf1, f32_0|f32_1)
    auto enc2 = [&](int l, const unsigned short* wqkv_p, const unsigned short* wm_p,
                    const unsigned short* w1_p, const unsigned short* w2_p) {
        // fused QKV: N=1536 (wqT|wkT|wvT contiguous rows); q cols -> poolA, kv cols -> poolB
        gemm_bf16<<<dim3(12, 256), 256, 0, stream>>>(fbf0, fbf0, wqkv_p, poolA, poolB,
            512, 512, 512, 512, 512, 512, 1024, 0);
        (void)hipMemsetAsync(kvws, 0, 266240ull * 4, stream);
        kv_reduce<<<dim3(16, 8, 8), 256, 0, stream>>>(poolB, kvws, ksumws);
        attn_msg<<<dim3(32, 4, 8), 256, 0, stream>>>(poolA, kvws, ksumws, poolC);
        gemm_bf16<<<dim3(4, 256), 256, 0, stream>>>(poolC, poolC, wm_p, poolA, poolA,
            512, 512, 512, 512, 512, 512, 512, 0);
        ln_fwd<<<8192, 256, 0, stream>>>(poolA, poolC, d_in[8], d_in[9], l, flagp);
        gemm_bf16<<<dim3(8, 256), 256, 0, stream>>>(fbf0, poolC, w1_p, poolB, poolB,
            1024, 512, 512, 1024, 1024, 1024, 1024, 1);
        gemm_bf16<<<dim3(4, 256), 256, 0, stream>>>(poolB, poolB, w2_p, poolA, poolA,
            1024, 1024, 1024, 1024, 512, 512, 512, 0);
        ln_res<<<8192, 256, 0, stream>>>(poolA, f32_0, fbf0, d_in[10], d_in[11], l, flagp);
    };

    for (int l = 0; l < 12; l++) {
        const unsigned short *wq_p, *wkv_p, *wm_p, *w1_p, *w2_p;
        if (preT) {
            unsigned short* base = wAll + (size_t)l * WPER;
            wq_p = base; wkv_p = base + 262144; wm_p = base + 786432;
            w1_p = base + 1048576; w2_p = base + 2097152;
        } else {
            transpose_in<<<dim3(16, 16), dim3(32, 8), 0, stream>>>(d_in[2], wqTl,            512, 512,  262144, l, 0, flagp);
            transpose_in<<<dim3(16, 16), dim3(32, 8), 0, stream>>>(d_in[3], wkvTl,           512, 512,  262144, l, 0, flagp);
            transpose_in<<<dim3(16, 16), dim3(32, 8), 0, stream>>>(d_in[4], wkvTl + 262144,  512, 512,  262144, l, 0, flagp);
            transpose_in<<<dim3(16, 16), dim3(32, 8), 0, stream>>>(d_in[5], wmTl,            512, 512,  262144, l, 0, flagp);
            transpose_in<<<dim3(32, 32), dim3(32, 8), 0, stream>>>(d_in[6], w1Tl,            1024, 1024, 1048576, l, 0, flagp);
            transpose_in<<<dim3(16, 32), dim3(32, 8), 0, stream>>>(d_in[7], w2Tl,            1024, 512,  524288, l, 0, flagp);
            wq_p = wqTl; wkv_p = wkvTl; wm_p = wmTl; w1_p = w1Tl; w2_p = w2Tl;
        }
        if ((l & 1) == 0) {  // self: batched across both feats
            if (preT) {
                enc2(l, wq_p /* wq|wk|wv contiguous */, wm_p, w1_p, w2_p);
            } else {
                enc1(f32_0, fbf0, fbf0, l, wq_p, wkv_p, wm_p, w1_p, w2_p);
                enc1(f32_1, fbf1, fbf1, l, wq_p, wkv_p, wm_p, w1_p, w2_p);
            }
        } else {             // cross (sequential: feat1 sees updated feat0)
            enc1(f32_0, fbf0, fbf1, l, wq_p, wkv_p, wm_p, w1_p, w2_p);
            enc1(f32_1, fbf1, fbf0, l, wq_p, wkv_p, wm_p, w1_p, w2_p);
        }
    }

    // Output: FLOAT32, (feat0, feat1) concatenated flat.
    (void)hipMemcpyAsync(d_out, f32_0, 8388608ull * 4, hipMemcpyDeviceToDevice, stream);
    (void)hipMemcpyAsync((char*)d_out + 8388608ull * 4, f32_1, 8388608ull * 4, hipMemcpyDeviceToDevice, stream);
}

// Round 6
// 7592.285 us; speedup vs baseline: 1.0837x; 1.0837x over previous
//
#include <hip/hip_runtime.h>

// ---------- types ----------
typedef __attribute__((ext_vector_type(8))) short short8;
typedef __attribute__((ext_vector_type(4))) float f32x4;
typedef __attribute__((ext_vector_type(8))) unsigned short ushort8;

__device__ inline float bf2f(unsigned short u) {
    unsigned int x = ((unsigned int)u) << 16;
    float f; __builtin_memcpy(&f, &x, 4); return f;
}
__device__ inline unsigned short f2bf(float f) {
    unsigned int x; __builtin_memcpy(&x, &f, 4);
    x += 0x7fffu + ((x >> 16) & 1u);
    return (unsigned short)(x >> 16);
}
// flag: 0 = fp32, 1 = bf16, 2 = fp16
__device__ inline float readf(const void* p, size_t i, int flag) {
    if (flag == 1) return bf2f(((const unsigned short*)p)[i]);
    if (flag == 2) return (float)(((const _Float16*)p)[i]);
    return ((const float*)p)[i];
}
__device__ inline float h2f(unsigned short u) {
    _Float16 h; __builtin_memcpy(&h, &u, 2); return (float)h;
}

// async global->LDS, 16B per lane. LDS dest must be wave-uniform base + lane*16.
__device__ __forceinline__ void gld_lds16(const unsigned short* g, unsigned short* l) {
    __builtin_amdgcn_global_load_lds(
        (const __attribute__((address_space(1))) unsigned int*)g,
        (__attribute__((address_space(3))) unsigned int*)l, 16, 0, 0);
}

// ---------- dtype detect from g1[0] == 1.0 ----------
__global__ void detect_dtype(const unsigned int* g1, int* flag) {
    unsigned int w = g1[0];
    int f = 0;
    if ((w & 0xFFFFu) == 0x3F80u) f = 1;       // bf16 1.0 pair
    else if ((w & 0xFFFFu) == 0x3C00u) f = 2;  // fp16 1.0 pair
    *flag = f;                                  // fp32 1.0 low16 = 0x0000 -> 0
}

// ---------- per-layer transpose -> bf16; out[z*outLS + c*R + r] = in[layer0+z][r][c] ----------
__global__ void transpose_in(const void* __restrict__ in, unsigned short* __restrict__ out,
                             int R, int Cc, size_t inBS, int layer0, size_t outLS,
                             const int* flagp) {
    int flag = *flagp;
    int layer = layer0 + blockIdx.z;
    unsigned short* op = out + (size_t)blockIdx.z * outLS;
    __shared__ unsigned short tile[32][33];
    int c0 = blockIdx.x * 32, r0 = blockIdx.y * 32;
#pragma unroll
    for (int j = 0; j < 4; j++) {
        int r = r0 + threadIdx.y + j * 8;
        size_t src = (size_t)layer * inBS + (size_t)r * Cc + c0 + threadIdx.x;
        tile[threadIdx.y + j * 8][threadIdx.x] = f2bf(readf(in, src, flag));
    }
    __syncthreads();
#pragma unroll
    for (int j = 0; j < 4; j++) {
        int c = c0 + threadIdx.y + j * 8;
        op[(size_t)c * R + r0 + threadIdx.x] = tile[threadIdx.x][threadIdx.y + j * 8];
    }
}

// ---------- feat convert (x8 vectorized): in -> fp32 master + bf16 shadow ----------
__global__ void cvt_feat(const void* __restrict__ in, float* __restrict__ f32,
                         unsigned short* __restrict__ fbf, int n, const int* flagp) {
    int flag = *flagp;
    int i = (blockIdx.x * 256 + threadIdx.x) * 8;
    if (i >= n) return;
    float v[8];
    if (flag == 1) {
        ushort8 r = *reinterpret_cast<const ushort8*>((const unsigned short*)in + i);
#pragma unroll
        for (int j = 0; j < 8; j++) { unsigned short us = r[j]; v[j] = bf2f(us); }
    } else if (flag == 2) {
        ushort8 r = *reinterpret_cast<const ushort8*>((const unsigned short*)in + i);
#pragma unroll
        for (int j = 0; j < 8; j++) { unsigned short us = r[j]; v[j] = h2f(us); }
    } else {
        float4 a = *reinterpret_cast<const float4*>((const float*)in + i);
        float4 b = *reinterpret_cast<const float4*>((const float*)in + i + 4);
        v[0] = a.x; v[1] = a.y; v[2] = a.z; v[3] = a.w;
        v[4] = b.x; v[5] = b.y; v[6] = b.z; v[7] = b.w;
    }
    *reinterpret_cast<float4*>(f32 + i) = make_float4(v[0], v[1], v[2], v[3]);
    *reinterpret_cast<float4*>(f32 + i + 4) = make_float4(v[4], v[5], v[6], v[7]);
    ushort8 o;
#pragma unroll
    for (int j = 0; j < 8; j++) o[j] = f2bf(v[j]);
    *reinterpret_cast<ushort8*>(fbf + i) = o;
}

// ---------- MFMA GEMM: m97 structure with BK=64 (2 K-slices per barrier pair) ----------
// C[M,N] = A[.,K] @ BT[.,K]^T. Halves barrier-drain count vs BK=32: the
// vmcnt(0)+lgkmcnt(0) drain before each s_barrier is the known ~20% stall of
// this 2-barrier structure; 32 MFMA per drain instead of 16. LDS 32 KB/block
// (>=3 blocks/CU still; BK=128's 64 KB occupancy cliff avoided).
// A split: k0 < splitK -> A, else A2 at k0-splitK (both lda; splitK % 64 == 0).
__global__ __launch_bounds__(256) void gemm_bf16(
    const unsigned short* __restrict__ A, const unsigned short* __restrict__ A2,
    const unsigned short* __restrict__ BT, unsigned short* __restrict__ C,
    int K, int lda, int splitK, int ldb, int ldc, int relu) {
    __shared__ __align__(16) unsigned short As[128 * 64];
    __shared__ __align__(16) unsigned short Bs[128 * 64];
    int t = threadIdx.x;
    int rowBase = blockIdx.y * 128, colBase = blockIdx.x * 128;
    int lane = t & 63, wave = t >> 6;
    int wm = (wave & 1) * 64, wn = (wave >> 1) * 64;
    int mrow = lane & 15, quad = lane >> 4;
    f32x4 acc[4][4];
#pragma unroll
    for (int i = 0; i < 4; i++)
#pragma unroll
        for (int j = 0; j < 4; j++) acc[i][j] = (f32x4){0.f, 0.f, 0.f, 0.f};

    // staging: chunk c (0..3) covers rows c*32 + (t>>3), col (t&7)*8 of [128][64];
    // LDS elem offset = c*2048 + t*8 (wave-uniform base + lane*16 bytes).
    int sr = t >> 3, sc = (t & 7) * 8;

    for (int k0 = 0; k0 < K; k0 += 64) {
        const unsigned short* Ab; int kk;
        if (k0 < splitK) { Ab = A; kk = k0; } else { Ab = A2; kk = k0 - splitK; }
        __syncthreads();  // previous iteration's LDS reads complete
#pragma unroll
        for (int c = 0; c < 4; c++) {
            gld_lds16(Ab + (size_t)(rowBase + c * 32 + sr) * lda + kk + sc, &As[c * 2048 + t * 8]);
            gld_lds16(BT + (size_t)(colBase + c * 32 + sr) * ldb + k0 + sc, &Bs[c * 2048 + t * 8]);
        }
        __syncthreads();  // drain: data in LDS
#pragma unroll
        for (int ks = 0; ks < 2; ks++) {
            short8 af[4], bfr[4];
#pragma unroll
            for (int mt = 0; mt < 4; mt++)
                af[mt] = *reinterpret_cast<const short8*>(&As[(wm + mt * 16 + mrow) * 64 + ks * 32 + quad * 8]);
#pragma unroll
            for (int nt = 0; nt < 4; nt++)
                bfr[nt] = *reinterpret_cast<const short8*>(&Bs[(wn + nt * 16 + mrow) * 64 + ks * 32 + quad * 8]);
#pragma unroll
            for (int mt = 0; mt < 4; mt++)
#pragma unroll
                for (int nt = 0; nt < 4; nt++)
                    acc[mt][nt] = __builtin_amdgcn_mfma_f32_16x16x32_bf16(af[mt], bfr[nt], acc[mt][nt], 0, 0, 0);
        }
    }
#pragma unroll
    for (int mt = 0; mt < 4; mt++)
#pragma unroll
        for (int nt = 0; nt < 4; nt++)
#pragma unroll
            for (int r = 0; r < 4; r++) {
                int row = rowBase + wm + mt * 16 + quad * 4 + r;
                int col = colBase + wn + nt * 16 + mrow;
                float v = acc[mt][nt][r];
                if (relu) v = fmaxf(v, 0.f);
                C[(size_t)row * ldc + col] = f2bf(v);
            }
}

// ---------- KV reduce (register-tiled 8x8, round-3 proven) ----------
// KV[n,h,d,e] += sum_s elu1(k[s,d]) * v[s,e]; Ksum[n,h,d] += sum elu1(k).
// kv buffer: [rows,1024] cols 0..511 = k, 512..1023 = v. grid (16 schunk, 8 h, nBatch)
__global__ __launch_bounds__(256) void kv_reduce(
    const unsigned short* __restrict__ kv, float* __restrict__ KV, float* __restrict__ Ksum) {
    __shared__ float smem[4096];          // kf = smem[0..2047], vf = smem[2048..4095]
    float* kf = smem;
    float* vf = smem + 2048;
    int t = threadIdx.x;
    int sc = blockIdx.x, h = blockIdx.y, n = blockIdx.z;
    int w = t >> 6, u = t & 63;
    int d0 = (u >> 3) * 8, e0 = (u & 7) * 8;
    float acc[8][8];
#pragma unroll
    for (int i = 0; i < 8; i++)
#pragma unroll
        for (int j = 0; j < 8; j++) acc[i][j] = 0.f;
    float ks[8];
#pragma unroll
    for (int i = 0; i < 8; i++) ks[i] = 0.f;

    int rl = t >> 3, dg = (t & 7) << 3;   // staging: 32 rows x 64 cols
    for (int sb = 0; sb < 8; sb++) {
        int srow = n * 4096 + sc * 256 + sb * 32 + rl;
        const unsigned short* kp = kv + (size_t)srow * 1024 + h * 64 + dg;
        ushort8 kr = *reinterpret_cast<const ushort8*>(kp);
        ushort8 vr = *reinterpret_cast<const ushort8*>(kp + 512);
        __syncthreads();
#pragma unroll
        for (int j = 0; j < 8; j++) {
            unsigned short ku = kr[j], vu = vr[j];
            float x = bf2f(ku);
            kf[rl * 64 + dg + j] = x > 0.f ? x + 1.f : __expf(x);
            vf[rl * 64 + dg + j] = bf2f(vu);
        }
        __syncthreads();
        // this wave's 8 s-rows of the 32-row tile
#pragma unroll
        for (int r = 0; r < 8; r++) {
            int s = w * 8 + r;
            float4 ka = *reinterpret_cast<const float4*>(&kf[s * 64 + d0]);
            float4 kb = *reinterpret_cast<const float4*>(&kf[s * 64 + d0 + 4]);
            float4 va = *reinterpret_cast<const float4*>(&vf[s * 64 + e0]);
            float4 vb = *reinterpret_cast<const float4*>(&vf[s * 64 + e0 + 4]);
            float kreg[8] = {ka.x, ka.y, ka.z, ka.w, kb.x, kb.y, kb.z, kb.w};
            float vreg[8] = {va.x, va.y, va.z, va.w, vb.x, vb.y, vb.z, vb.w};
#pragma unroll
            for (int i = 0; i < 8; i++) ks[i] += kreg[i];
#pragma unroll
            for (int i = 0; i < 8; i++)
#pragma unroll
                for (int j = 0; j < 8; j++) acc[i][j] += kreg[i] * vreg[j];
        }
    }
    // merge the 4 waves' duplicated 64x64 tiles in LDS
    __syncthreads();
    if (w == 0) {
#pragma unroll
        for (int i = 0; i < 8; i++)
#pragma unroll
            for (int j = 0; j < 8; j++) smem[(d0 + i) * 64 + e0 + j] = acc[i][j];
    }
    __syncthreads();
#pragma unroll
    for (int ww = 1; ww < 4; ww++) {
        if (w == ww) {
#pragma unroll
            for (int i = 0; i < 8; i++)
#pragma unroll
                for (int j = 0; j < 8; j++) smem[(d0 + i) * 64 + e0 + j] += acc[i][j];
        }
        __syncthreads();
    }
    float* dst = KV + ((size_t)(n * 8 + h) << 12);
#pragma unroll
    for (int i = 0; i < 16; i++) {
        int idx = t + i * 256;
        atomicAdd(dst + idx, smem[idx]);
    }
    if ((u & 7) == 0) {
#pragma unroll
        for (int i = 0; i < 8; i++)
            atomicAdd(Ksum + (n * 8 + h) * 64 + d0 + i, ks[i]);
    }
}

// ---------- attention message (wave-local, zero barriers, round-1 proven) ----------
// msg[l, h*64+e] = elu1(Q).KV / (elu1(Q).Ksum + eps). grid (32 rowchunk, 4 headpair, nBatch)
__global__ __launch_bounds__(256) void attn_msg(
    const unsigned short* __restrict__ q, const float* __restrict__ KV,
    const float* __restrict__ Ksum, unsigned short* __restrict__ msg) {
    __shared__ __align__(16) float qsh[4][128];
    int t = threadIdx.x;
    int rcb = blockIdx.x, hp = blockIdx.y, n = blockIdx.z;
    int h0 = hp * 2;
    int w = t >> 6, lane = t & 63;

    // hoist this thread's two KV columns (e = lane) into registers
    const float* kvp = KV + (size_t)(n * 8 + h0) * 4096 + lane;
    float kv0[64], kv1[64];
#pragma unroll
    for (int d = 0; d < 64; d++) kv0[d] = kvp[d * 64];
#pragma unroll
    for (int d = 0; d < 64; d++) kv1[d] = kvp[4096 + d * 64];
    const float* ksp = Ksum + (size_t)(n * 8 + h0) * 64;
    float ks0 = ksp[lane * 2], ks1 = ksp[lane * 2 + 1];  // spans [head0 | head1]

    for (int it = 0; it < 32; it++) {
        int row = rcb * 128 + it * 4 + w;
        unsigned int raw = *reinterpret_cast<const unsigned int*>(
            q + (size_t)(n * 4096 + row) * 512 + h0 * 64 + lane * 2);
        float x0 = bf2f((unsigned short)(raw & 0xFFFFu));
        float x1 = bf2f((unsigned short)(raw >> 16));
        x0 = x0 > 0.f ? x0 + 1.f : __expf(x0);
        x1 = x1 > 0.f ? x1 + 1.f : __expf(x1);
        // z: halves-reduction (xor offsets 1..16 stay within 32-lane halves)
        float part = x0 * ks0 + x1 * ks1;
#pragma unroll
        for (int off = 1; off < 32; off <<= 1) part += __shfl_xor(part, off, 64);
        float z0 = 1.f / (__shfl(part, 0, 64) + 1e-6f);
        float z1 = 1.f / (__shfl(part, 32, 64) + 1e-6f);
        // wave-local broadcast of the q row (in-wave DS ordering, no barrier)
        qsh[w][lane * 2] = x0;
        qsh[w][lane * 2 + 1] = x1;
        float a0 = 0.f, a1 = 0.f;
#pragma unroll
        for (int d4 = 0; d4 < 16; d4++) {
            float4 qa = *reinterpret_cast<const float4*>(&qsh[w][d4 * 4]);
            float4 qb = *reinterpret_cast<const float4*>(&qsh[w][64 + d4 * 4]);
            a0 += qa.x * kv0[d4 * 4] + qa.y * kv0[d4 * 4 + 1] +
                  qa.z * kv0[d4 * 4 + 2] + qa.w * kv0[d4 * 4 + 3];
            a1 += qb.x * kv1[d4 * 4] + qb.y * kv1[d4 * 4 + 1] +
                  qb.z * kv1[d4 * 4 + 2] + qb.w * kv1[d4 * 4 + 3];
        }
        unsigned short* mp = msg + (size_t)(n * 4096 + row) * 512 + h0 * 64;
        mp[lane] = f2bf(a0 * z0);
        mp[64 + lane] = f2bf(a1 * z1);
    }
}

// ---------- LayerNorm (C=512), wave per row ----------
__global__ __launch_bounds__(256) void ln_fwd(
    const unsigned short* __restrict__ in, unsigned short* __restrict__ out,
    const void* __restrict__ g, const void* __restrict__ b, int layer, const int* flagp) {
    int flag = *flagp;
    int wave = threadIdx.x >> 6, lane = threadIdx.x & 63;
    size_t row = (size_t)blockIdx.x * 4 + wave;
    ushort8 raw = *reinterpret_cast<const ushort8*>(in + row * 512 + lane * 8);
    float x[8], s = 0.f, sq = 0.f;
#pragma unroll
    for (int j = 0; j < 8; j++) { unsigned short us = raw[j]; x[j] = bf2f(us); s += x[j]; sq += x[j] * x[j]; }
#pragma unroll
    for (int off = 1; off < 64; off <<= 1) { s += __shfl_xor(s, off, 64); sq += __shfl_xor(sq, off, 64); }
    float mu = s * (1.f / 512.f);
    float var = fmaxf(sq * (1.f / 512.f) - mu * mu, 0.f);
    float rs = rsqrtf(var + 1e-5f);
    int c = layer * 512 + lane * 8;
    ushort8 o;
#pragma unroll
    for (int j = 0; j < 8; j++) {
        float gv = readf(g, c + j, flag);
        float bv = readf(b, c + j, flag);
        o[j] = f2bf((x[j] - mu) * rs * gv + bv);
    }
    *reinterpret_cast<ushort8*>(out + row * 512 + lane * 8) = o;
}

// ---------- LayerNorm + residual: f32 += LN(u); refresh bf16 shadow ----------
__global__ __launch_bounds__(256) void ln_res(
    const unsigned short* __restrict__ u, float* __restrict__ f32,
    unsigned short* __restrict__ fbf, const void* __restrict__ g,
    const void* __restrict__ b, int layer, const int* flagp) {
    int flag = *flagp;
    int wave = threadIdx.x >> 6, lane = threadIdx.x & 63;
    size_t row = (size_t)blockIdx.x * 4 + wave;
    ushort8 raw = *reinterpret_cast<const ushort8*>(u + row * 512 + lane * 8);
    float x[8], s = 0.f, sq = 0.f;
#pragma unroll
    for (int j = 0; j < 8; j++) { unsigned short us = raw[j]; x[j] = bf2f(us); s += x[j]; sq += x[j] * x[j]; }
#pragma unroll
    for (int off = 1; off < 64; off <<= 1) { s += __shfl_xor(s, off, 64); sq += __shfl_xor(sq, off, 64); }
    float mu = s * (1.f / 512.f);
    float var = fmaxf(sq * (1.f / 512.f) - mu * mu, 0.f);
    float rs = rsqrtf(var + 1e-5f);
    int c = layer * 512 + lane * 8;
    float* fp = f32 + row * 512 + lane * 8;
    float4 f0 = *reinterpret_cast<float4*>(fp);
    float4 f1 = *reinterpret_cast<float4*>(fp + 4);
    float fv[8] = {f0.x, f0.y, f0.z, f0.w, f1.x, f1.y, f1.z, f1.w};
    ushort8 o;
#pragma unroll
    for (int j = 0; j < 8; j++) {
        float gv = readf(g, c + j, flag);
        float bv = readf(b, c + j, flag);
        float y = (x[j] - mu) * rs * gv + bv;
        fv[j] += y;
        o[j] = f2bf(fv[j]);
    }
    f0 = make_float4(fv[0], fv[1], fv[2], fv[3]);
    f1 = make_float4(fv[4], fv[5], fv[6], fv[7]);
    *reinterpret_cast<float4*>(fp) = f0;
    *reinterpret_cast<float4*>(fp + 4) = f1;
    *reinterpret_cast<ushort8*>(fbf + row * 512 + lane * 8) = o;
}

// ---------- host ----------
// Output d_out is FLOAT32 (reference output dtype), (feat0, feat1) concat flat.
// ROUND 11: revert round-5 self-layer batching (regressed: destroyed producer->
// consumer L2 locality at 96 MB working set). Back to enc1-only round-3 path.
// ONE isolated GEMM change: BK=64 (barrier drains halved, 32 MFMA per drain).
extern "C" void kernel_launch(void* const* d_in, const int* in_sizes, int n_in,
                              void* d_out, int out_size, void* d_ws, size_t ws_size,
                              hipStream_t stream) {
    char* ws = (char*)d_ws;
    size_t o = 0;
    auto take = [&](size_t bytes) { char* p = ws + o; o += (bytes + 1023) & ~(size_t)1023; return p; };
    // per-layer fallback weight buffers (always reserved; 5 MB)
    unsigned short* wqTl  = (unsigned short*)take(262144ull * 2);
    unsigned short* wkvTl = (unsigned short*)take(524288ull * 2);
    unsigned short* wmTl  = (unsigned short*)take(262144ull * 2);
    unsigned short* w1Tl  = (unsigned short*)take(1048576ull * 2);
    unsigned short* w2Tl  = (unsigned short*)take(524288ull * 2);
    float* f32_0 = (float*)take(8388608ull * 4);
    float* f32_1 = (float*)take(8388608ull * 4);
    unsigned short* fbf0  = (unsigned short*)take(8388608ull * 2);
    unsigned short* fbf1  = (unsigned short*)take(8388608ull * 2);
    unsigned short* poolA = (unsigned short*)take(8388608ull * 2);
    unsigned short* poolB = (unsigned short*)take(16777216ull * 2);
    unsigned short* poolC = (unsigned short*)take(8388608ull * 2);
    float* kvws = (float*)take(133120ull * 4);  // KV[4*8*64*64] then Ksum[4*8*64]
    int* flagp = (int*)take(64);
    float* ksumws = kvws + 131072;

    // batched all-layer weight area (60 MB), used only if workspace allows
    const size_t WPER = 2621440ull;  // shorts per layer: wq|wk|wv|wm|w1|w2
    bool preT = ws_size >= o + WPER * 12ull * 2ull + 65536ull;
    unsigned short* wAll = preT ? (unsigned short*)take(WPER * 12ull * 2ull) : nullptr;

    detect_dtype<<<1, 1, 0, stream>>>((const unsigned int*)d_in[8], flagp);
    cvt_feat<<<4096, 256, 0, stream>>>(d_in[0], f32_0, fbf0, 8388608, flagp);
    cvt_feat<<<4096, 256, 0, stream>>>(d_in[1], f32_1, fbf1, 8388608, flagp);

    if (preT) {  // all 12 layers transposed in 6 dispatches
        transpose_in<<<dim3(16, 16, 12), dim3(32, 8), 0, stream>>>(d_in[2], wAll,           512, 512,  262144, 0, WPER, flagp);
        transpose_in<<<dim3(16, 16, 12), dim3(32, 8), 0, stream>>>(d_in[3], wAll + 262144,  512, 512,  262144, 0, WPER, flagp);
        transpose_in<<<dim3(16, 16, 12), dim3(32, 8), 0, stream>>>(d_in[4], wAll + 524288,  512, 512,  262144, 0, WPER, flagp);
        transpose_in<<<dim3(16, 16, 12), dim3(32, 8), 0, stream>>>(d_in[5], wAll + 786432,  512, 512,  262144, 0, WPER, flagp);
        transpose_in<<<dim3(32, 32, 12), dim3(32, 8), 0, stream>>>(d_in[6], wAll + 1048576, 1024, 1024, 1048576, 0, WPER, flagp);
        transpose_in<<<dim3(16, 32, 12), dim3(32, 8), 0, stream>>>(d_in[7], wAll + 2097152, 1024, 512,  524288, 0, WPER, flagp);
    }

    auto enc = [&](float* xf32, unsigned short* xbf, const unsigned short* srcbf, int l,
                   const unsigned short* wq_p, const unsigned short* wkv_p, const unsigned short* wm_p,
                   const unsigned short* w1_p, const unsigned short* w2_p) {
        gemm_bf16<<<dim3(4, 128), 256, 0, stream>>>(xbf, xbf, wq_p, poolA,
            512, 512, 512, 512, 512, 0);
        gemm_bf16<<<dim3(8, 128), 256, 0, stream>>>(srcbf, srcbf, wkv_p, poolB,
            512, 512, 512, 512, 1024, 0);
        (void)hipMemsetAsync(kvws, 0, 133120ull * 4, stream);
        kv_reduce<<<dim3(16, 8, 4), 256, 0, stream>>>(poolB, kvws, ksumws);
        attn_msg<<<dim3(32, 4, 4), 256, 0, stream>>>(poolA, kvws, ksumws, poolC);
        gemm_bf16<<<dim3(4, 128), 256, 0, stream>>>(poolC, poolC, wm_p, poolA,
            512, 512, 512, 512, 512, 0);
        ln_fwd<<<4096, 256, 0, stream>>>(poolA, poolC, d_in[8], d_in[9], l, flagp);
        gemm_bf16<<<dim3(8, 128), 256, 0, stream>>>(xbf, poolC, w1_p, poolB,
            1024, 512, 512, 1024, 1024, 1);
        gemm_bf16<<<dim3(4, 128), 256, 0, stream>>>(poolB, poolB, w2_p, poolA,
            1024, 1024, 1024, 1024, 512, 0);
        ln_res<<<4096, 256, 0, stream>>>(poolA, xf32, xbf, d_in[10], d_in[11], l, flagp);
    };

    for (int l = 0; l < 12; l++) {
        const unsigned short *wq_p, *wkv_p, *wm_p, *w1_p, *w2_p;
        if (preT) {
            unsigned short* base = wAll + (size_t)l * WPER;
            wq_p = base; wkv_p = base + 262144; wm_p = base + 786432;
            w1_p = base + 1048576; w2_p = base + 2097152;
        } else {
            transpose_in<<<dim3(16, 16), dim3(32, 8), 0, stream>>>(d_in[2], wqTl,            512, 512,  262144, l, 0, flagp);
            transpose_in<<<dim3(16, 16), dim3(32, 8), 0, stream>>>(d_in[3], wkvTl,           512, 512,  262144, l, 0, flagp);
            transpose_in<<<dim3(16, 16), dim3(32, 8), 0, stream>>>(d_in[4], wkvTl + 262144,  512, 512,  262144, l, 0, flagp);
            transpose_in<<<dim3(16, 16), dim3(32, 8), 0, stream>>>(d_in[5], wmTl,            512, 512,  262144, l, 0, flagp);
            transpose_in<<<dim3(32, 32), dim3(32, 8), 0, stream>>>(d_in[6], w1Tl,            1024, 1024, 1048576, l, 0, flagp);
            transpose_in<<<dim3(16, 32), dim3(32, 8), 0, stream>>>(d_in[7], w2Tl,            1024, 512,  524288, l, 0, flagp);
            wq_p = wqTl; wkv_p = wkvTl; wm_p = wmTl; w1_p = w1Tl; w2_p = w2Tl;
        }
        if ((l & 1) == 0) {  // self
            enc(f32_0, fbf0, fbf0, l, wq_p, wkv_p, wm_p, w1_p, w2_p);
            enc(f32_1, fbf1, fbf1, l, wq_p, wkv_p, wm_p, w1_p, w2_p);
        } else {             // cross (sequential: feat1 sees updated feat0)
            enc(f32_0, fbf0, fbf1, l, wq_p, wkv_p, wm_p, w1_p, w2_p);
            enc(f32_1, fbf1, fbf0, l, wq_p, wkv_p, wm_p, w1_p, w2_p);
        }
    }

    // Output: FLOAT32, (feat0, feat1) concatenated flat.
    (void)hipMemcpyAsync(d_out, f32_0, 8388608ull * 4, hipMemcpyDeviceToDevice, stream);
    (void)hipMemcpyAsync((char*)d_out + 8388608ull * 4, f32_1, 8388608ull * 4, hipMemcpyDeviceToDevice, stream);
}